// Round 1
// baseline (251.634 us; speedup 1.0000x reference)
//
#include <hip/hip_runtime.h>
#include <hip/hip_bf16.h>

// Sobel gradient magnitude (L1) with SAME zero padding.
// Input:  x (32, 1, 1024, 1024) fp32
// Output: |conv(x, Sx)| + |conv(x, Sy)| + 1e-5, same shape.
//
// Layout: one block per image row (H*N = 32768 blocks), 256 threads/block,
// each thread computes 4 contiguous outputs (float4 stores). Per thread we
// load float4 + 2 halo scalars from each of the 3 input rows; row reuse
// (each input row read by 3 blocks) is served by L1/L2.

#define W 1024
#define H 1024
#define EPS 1e-5f

__global__ __launch_bounds__(256) void sobel_kernel(const float* __restrict__ in,
                                                    float* __restrict__ out) {
    const int rowid = blockIdx.x;          // 0 .. N*H-1
    const int img = rowid >> 10;           // / H
    const int y = rowid & (H - 1);
    const int x0 = threadIdx.x << 2;       // 4 outputs per thread

    const size_t img_off = (size_t)img * W * H;
    const float* rm = in + img_off + (size_t)y * W;

    // middle row
    float4 mv = *(const float4*)(rm + x0);
    float ml = (x0 > 0) ? rm[x0 - 1] : 0.0f;
    float mr = (x0 + 4 < W) ? rm[x0 + 4] : 0.0f;

    // top row (zero pad at y==0)
    float4 tv = make_float4(0.f, 0.f, 0.f, 0.f);
    float tl = 0.f, tr = 0.f;
    if (y > 0) {
        const float* rt = rm - W;
        tv = *(const float4*)(rt + x0);
        tl = (x0 > 0) ? rt[x0 - 1] : 0.0f;
        tr = (x0 + 4 < W) ? rt[x0 + 4] : 0.0f;
    }

    // bottom row (zero pad at y==H-1)
    float4 bv = make_float4(0.f, 0.f, 0.f, 0.f);
    float bl = 0.f, br = 0.f;
    if (y < H - 1) {
        const float* rb = rm + W;
        bv = *(const float4*)(rb + x0);
        bl = (x0 > 0) ? rb[x0 - 1] : 0.0f;
        br = (x0 + 4 < W) ? rb[x0 + 4] : 0.0f;
    }

    const float T[6] = {tl, tv.x, tv.y, tv.z, tv.w, tr};
    const float M[6] = {ml, mv.x, mv.y, mv.z, mv.w, mr};
    const float B[6] = {bl, bv.x, bv.y, bv.z, bv.w, br};

    float4 o;
    float* op = &o.x;
#pragma unroll
    for (int i = 0; i < 4; ++i) {
        // Sobel X: [[-1,0,1],[-2,0,2],[-1,0,1]]
        float gx = (T[i + 2] - T[i]) + 2.0f * (M[i + 2] - M[i]) + (B[i + 2] - B[i]);
        // Sobel Y: [[-1,-2,-1],[0,0,0],[1,2,1]]
        float gy = (B[i] + 2.0f * B[i + 1] + B[i + 2]) - (T[i] + 2.0f * T[i + 1] + T[i + 2]);
        op[i] = fabsf(gx) + fabsf(gy) + EPS;
    }

    *(float4*)(out + img_off + (size_t)y * W + x0) = o;
}

extern "C" void kernel_launch(void* const* d_in, const int* in_sizes, int n_in,
                              void* d_out, int out_size, void* d_ws, size_t ws_size,
                              hipStream_t stream) {
    const float* x = (const float*)d_in[0];
    float* out = (float*)d_out;
    const int N = 32;
    dim3 grid(N * H);
    dim3 block(256);
    sobel_kernel<<<grid, block, 0, stream>>>(x, out);
}

// Round 3
// 237.344 us; speedup vs baseline: 1.0602x; 1.0602x over previous
//
#include <hip/hip_runtime.h>
#include <hip/hip_bf16.h>

// Sobel |gx|+|gy|+eps, SAME zero padding. Input (32,1,1024,1024) fp32.
//
// R3: register sliding-window over y (R2 logic; fixed nontemporal-store type —
// __builtin_nontemporal_store needs a native vector, not HIP_vector_type).
// One block per (image, 16-row strip), full 1024-wide row per block
// (256 thr x float4). Per output row each thread loads only the NEW bottom
// row (1 vec4 + 2 halo scalars), reusing the two rows above from registers
// -> logical input reads drop 3x -> 1.125x. XCD swizzle groups 8 adjacent
// strips per XCD for halo L2 locality. Nontemporal stores keep the write
// stream from evicting cached input rows.

#define W 1024
#define H 1024
#define R 16          // rows per block strip (64 strips/image)
#define EPS 1e-5f

typedef float v4f __attribute__((ext_vector_type(4)));

__device__ __forceinline__ void loadrow(const float* __restrict__ base, int y,
                                        int x0, float* dst) {
    if (y < 0 || y >= H) {
        dst[0] = dst[1] = dst[2] = dst[3] = dst[4] = dst[5] = 0.f;
        return;
    }
    const float* r = base + (size_t)y * W;
    v4f v = *(const v4f*)(r + x0);
    dst[1] = v.x; dst[2] = v.y; dst[3] = v.z; dst[4] = v.w;
    dst[0] = (x0 > 0) ? r[x0 - 1] : 0.f;
    dst[5] = (x0 + 4 < W) ? r[x0 + 4] : 0.f;
}

__global__ __launch_bounds__(256) void sobel_kernel(const float* __restrict__ in,
                                                    float* __restrict__ out) {
    // XCD swizzle: blocks b, b+256, b+512, ... (same XCD under round-robin %8,
    // since 256%8==0) handle 8 ADJACENT strips -> shared halo rows stay in
    // that XCD's L2.
    const int b = blockIdx.x;                 // 0..2047
    const int t = ((b & 255) << 3) | (b >> 8);// bijective swizzle
    const int img = t >> 6;                   // 64 strips per image
    const int ty = (t & 63) * R;              // first output row of strip
    const int x0 = threadIdx.x << 2;

    const float* base = in + (size_t)img * (W * H);
    float* obase = out + (size_t)img * (W * H);

    float T[6], M[6], B[6], Nx[6];
    loadrow(base, ty - 1, x0, T);
    loadrow(base, ty,     x0, M);
    loadrow(base, ty + 1, x0, B);

#pragma unroll 4
    for (int i = 0; i < R; ++i) {
        const int y = ty + i;
        // prefetch the row needed NEXT iteration while computing this one
        loadrow(base, y + 2, x0, Nx);

        v4f o;
#pragma unroll
        for (int j = 0; j < 4; ++j) {
            // Sobel X: [[-1,0,1],[-2,0,2],[-1,0,1]]
            float gx = (T[j + 2] - T[j]) + 2.0f * (M[j + 2] - M[j]) + (B[j + 2] - B[j]);
            // Sobel Y: [[-1,-2,-1],[0,0,0],[1,2,1]]
            float gy = (B[j] + 2.0f * B[j + 1] + B[j + 2]) - (T[j] + 2.0f * T[j + 1] + T[j + 2]);
            o[j] = fabsf(gx) + fabsf(gy) + EPS;
        }
        __builtin_nontemporal_store(o, (v4f*)(obase + (size_t)y * W + x0));

#pragma unroll
        for (int j = 0; j < 6; ++j) { T[j] = M[j]; M[j] = B[j]; B[j] = Nx[j]; }
    }
}

extern "C" void kernel_launch(void* const* d_in, const int* in_sizes, int n_in,
                              void* d_out, int out_size, void* d_ws, size_t ws_size,
                              hipStream_t stream) {
    const float* x = (const float*)d_in[0];
    float* out = (float*)d_out;
    const int N = 32;
    dim3 grid(N * (H / R));   // 32 * 64 = 2048 blocks
    dim3 block(256);
    sobel_kernel<<<grid, block, 0, stream>>>(x, out);
}